// Round 15
// baseline (666.832 us; speedup 1.0000x reference)
//
#include <hip/hip_runtime.h>
#include <hip/hip_cooperative_groups.h>

constexpr int FIN = 512;
constexpr int FH  = 128;
constexpr int FO  = 64;

typedef short short8 __attribute__((ext_vector_type(8)));
typedef float f32x4 __attribute__((ext_vector_type(4)));

__device__ __forceinline__ unsigned short f2bf(float f) {
    unsigned u = __float_as_uint(f);
    u += 0x7fffu + ((u >> 16) & 1u);   // RNE
    return (unsigned short)(u >> 16);
}
__device__ __forceinline__ float bf2f(unsigned short h) {
    return __uint_as_float((unsigned)h << 16);
}
__device__ __forceinline__ float bflo(unsigned v) { return __uint_as_float(v << 16); }
__device__ __forceinline__ float bfhi(unsigned v) { return __uint_as_float(v & 0xffff0000u); }

// ---------------- ONE cooperative kernel: clear|convW -> count -> scan+dinv -> fill
// Replaces 6 small serialized dispatches (clear, pre, scan1, scan2, scan3, fill).
// Phase bodies are byte-ports of the round-12 kernels; numerics identical.

__global__ void build_kernel(const int* __restrict__ src, const int* __restrict__ dst,
                             int E, int n,
                             const float* __restrict__ W1, unsigned short* __restrict__ W1b,
                             const float* __restrict__ Wmu, const float* __restrict__ Wlg,
                             unsigned short* __restrict__ W2h, unsigned short* __restrict__ W2l,
                             int* __restrict__ cnt, int* __restrict__ offs,
                             int* __restrict__ bsum, float* __restrict__ dinv,
                             int2* __restrict__ esort) {
    namespace cg = cooperative_groups;
    cg::grid_group grid = cg::this_grid();
    __shared__ int sdata[256];

    int tid = threadIdx.x;
    int gtid = blockIdx.x * blockDim.x + tid;
    int gthreads = gridDim.x * blockDim.x;     // 262144

    // ---- phase A: clear cnt | convert W1 -> bf16 | convert W2 -> hi/lo bf16 ----
    for (int i = gtid; i < n; i += gthreads) cnt[i] = 0;
    for (int i = gtid; i < FH * FIN / 4; i += gthreads) {      // 16384 float4s
        float4 v = ((const float4*)W1)[i];
        ushort4 p;
        p.x = f2bf(v.x); p.y = f2bf(v.y); p.z = f2bf(v.z); p.w = f2bf(v.w);
        ((ushort4*)W1b)[i] = p;
    }
    for (int i = gtid; i < FH * FH; i += gthreads) {           // 16384 elems
        int r = i >> 7, c = i & 127;
        float f = (r < 64) ? Wmu[r * 128 + c] : Wlg[(r - 64) * 128 + c];
        unsigned short h = f2bf(f);
        W2h[i] = h;
        W2l[i] = f2bf(f - bf2f(h));
    }
    grid.sync();

    // ---- phase B: count in-degrees ----
    for (int i = gtid; i < E; i += gthreads) atomicAdd(&cnt[dst[i]], 1);
    grid.sync();

    // ---- phase C1: per-1024 block scans (blocks 0..nb-1) + dinv (all blocks) ----
    int nb = (n + 1023) >> 10;                 // 49
    if (blockIdx.x < nb) {
        int base = blockIdx.x * 1024 + tid * 4;
        int4 c = make_int4(0, 0, 0, 0);
        if (base + 3 < n) {
            c = *(const int4*)(cnt + base);
        } else {
            if (base + 0 < n) c.x = cnt[base + 0];
            if (base + 1 < n) c.y = cnt[base + 1];
            if (base + 2 < n) c.z = cnt[base + 2];
            if (base + 3 < n) c.w = cnt[base + 3];
        }
        if (base + 0 < n) dinv[base + 0] = rsqrtf((float)(c.x + 1));
        if (base + 1 < n) dinv[base + 1] = rsqrtf((float)(c.y + 1));
        if (base + 2 < n) dinv[base + 2] = rsqrtf((float)(c.z + 1));
        if (base + 3 < n) dinv[base + 3] = rsqrtf((float)(c.w + 1));

        int s0 = c.x + c.y + c.z + c.w;
        sdata[tid] = s0;
        __syncthreads();
        for (int off = 1; off < 256; off <<= 1) {
            int v = (tid >= off) ? sdata[tid - off] : 0;
            __syncthreads();
            sdata[tid] += v;
            __syncthreads();
        }
        int excl = sdata[tid] - s0;
        if (tid == 255) bsum[blockIdx.x] = sdata[255];
        if (base + 0 < n) offs[base + 0] = excl;
        if (base + 1 < n) offs[base + 1] = excl + c.x;
        if (base + 2 < n) offs[base + 2] = excl + c.x + c.y;
        if (base + 3 < n) offs[base + 3] = excl + c.x + c.y + c.z;
    }
    grid.sync();

    // ---- phase C2: scan block sums (block 0) ----
    if (blockIdx.x == 0) {
        int v = (tid < nb) ? bsum[tid] : 0;
        sdata[tid] = v;
        __syncthreads();
        for (int off = 1; off < 256; off <<= 1) {
            int u = (tid >= off) ? sdata[tid - off] : 0;
            __syncthreads();
            sdata[tid] += u;
            __syncthreads();
        }
        if (tid < nb) bsum[tid] = sdata[tid] - v;  // exclusive
    }
    grid.sync();

    // ---- phase C3: apply block offsets ----
    for (int i = gtid; i < n; i += gthreads) offs[i] += bsum[i >> 10];
    if (gtid == 0) offs[n] = E;
    grid.sync();

    // ---- phase D: fill (slot via atomicSub on cnt) ----
    for (int i = gtid; i < E; i += gthreads) {
        int s = src[i];
        int d = dst[i];
        int old = atomicSub(&cnt[d], 1);
        int pos = offs[d] + old - 1;
        float w = dinv[s] * dinv[d];
        esort[pos] = make_int2(s, __float_as_int(w));
    }
}

// ---------------- SpMM gather (bf16 table), unroll-8 (round-12 proven) -------------

__global__ void spmm_kernel(const unsigned int* __restrict__ hin, const int* __restrict__ offs,
                            const int2* __restrict__ esort, const float* __restrict__ dinv,
                            const float* __restrict__ bias, unsigned int* __restrict__ hout,
                            int n, int relu) {
    int gid = blockIdx.x * blockDim.x + threadIdx.x;
    int node = gid >> 6;            // one 64-lane wave per node
    int lane = threadIdx.x & 63;    // lane handles channels 2*lane, 2*lane+1
    if (node >= n) return;
    float di = dinv[node];
    unsigned hv = hin[(size_t)node * 64 + lane];
    float ax = di * di * bflo(hv);
    float ay = di * di * bfhi(hv);
    int p = offs[node];
    int end = offs[node + 1];
    if ((p & 1) && p < end) {
        int2 e = esort[p];
        unsigned v = hin[(size_t)e.x * 64 + lane];
        float w = __int_as_float(e.y);
        ax = fmaf(w, bflo(v), ax); ay = fmaf(w, bfhi(v), ay);
        ++p;
    }
    for (; p + 8 <= end; p += 8) {
        int4 q0 = *(const int4*)(esort + p + 0);
        int4 q1 = *(const int4*)(esort + p + 2);
        int4 q2 = *(const int4*)(esort + p + 4);
        int4 q3 = *(const int4*)(esort + p + 6);
        unsigned v0 = hin[(size_t)q0.x * 64 + lane];
        unsigned v1 = hin[(size_t)q0.z * 64 + lane];
        unsigned v2 = hin[(size_t)q1.x * 64 + lane];
        unsigned v3 = hin[(size_t)q1.z * 64 + lane];
        unsigned v4 = hin[(size_t)q2.x * 64 + lane];
        unsigned v5 = hin[(size_t)q2.z * 64 + lane];
        unsigned v6 = hin[(size_t)q3.x * 64 + lane];
        unsigned v7 = hin[(size_t)q3.z * 64 + lane];
        float w0 = __int_as_float(q0.y), w1 = __int_as_float(q0.w);
        float w2 = __int_as_float(q1.y), w3 = __int_as_float(q1.w);
        float w4 = __int_as_float(q2.y), w5 = __int_as_float(q2.w);
        float w6 = __int_as_float(q3.y), w7 = __int_as_float(q3.w);
        ax = fmaf(w0, bflo(v0), ax); ay = fmaf(w0, bfhi(v0), ay);
        ax = fmaf(w1, bflo(v1), ax); ay = fmaf(w1, bfhi(v1), ay);
        ax = fmaf(w2, bflo(v2), ax); ay = fmaf(w2, bfhi(v2), ay);
        ax = fmaf(w3, bflo(v3), ax); ay = fmaf(w3, bfhi(v3), ay);
        ax = fmaf(w4, bflo(v4), ax); ay = fmaf(w4, bfhi(v4), ay);
        ax = fmaf(w5, bflo(v5), ax); ay = fmaf(w5, bfhi(v5), ay);
        ax = fmaf(w6, bflo(v6), ax); ay = fmaf(w6, bfhi(v6), ay);
        ax = fmaf(w7, bflo(v7), ax); ay = fmaf(w7, bfhi(v7), ay);
    }
    for (; p + 2 <= end; p += 2) {
        int4 q = *(const int4*)(esort + p);
        unsigned v0 = hin[(size_t)q.x * 64 + lane];
        unsigned v1 = hin[(size_t)q.z * 64 + lane];
        float w0 = __int_as_float(q.y), w1 = __int_as_float(q.w);
        ax = fmaf(w0, bflo(v0), ax); ay = fmaf(w0, bfhi(v0), ay);
        ax = fmaf(w1, bflo(v1), ax); ay = fmaf(w1, bfhi(v1), ay);
    }
    if (p < end) {
        int2 e = esort[p];
        unsigned v = hin[(size_t)e.x * 64 + lane];
        float w = __int_as_float(e.y);
        ax = fmaf(w, bflo(v), ax); ay = fmaf(w, bfhi(v), ay);
    }
    if (bias) {
        float2 b = ((const float2*)bias)[lane];
        ax += b.x; ay += b.y;
    }
    if (relu) { ax = fmaxf(ax, 0.f); ay = fmaxf(ay, 0.f); }
    unsigned o = (unsigned)f2bf(ax) | ((unsigned)f2bf(ay) << 16);
    hout[(size_t)node * 64 + lane] = o;
}

// ---------------- GEMM1: h[M,128](bf16) = X[M,512] @ W1b[128,512]^T ----------------
// Persistent whole-W1 in LDS (128KB, swizzled). Grid = 256 (one block/CU); strips
// dealt bijectively s = wid*grid + blk. Depth-1 prefetch (fits 64 VGPR, no scratch).

__global__ __launch_bounds__(1024, 4) void gemm1_kernel(
    const float* __restrict__ X, const unsigned short* __restrict__ Wb,
    unsigned short* __restrict__ out, int M, int nstrips) {
    extern __shared__ __align__(16) unsigned short Bs[];   // 128 KB
    int tid = threadIdx.x;

    #pragma unroll
    for (int j = 0; j < 8; ++j) {
        int f = tid + j * 1024;             // chunk id
        int row = f >> 6;                   // 64 chunks (1024B) per row
        unsigned addr = ((unsigned)f << 4) ^ ((unsigned)(row & 7) << 4);
        *(short8*)((char*)Bs + addr) = ((const short8*)Wb)[f];
    }
    __syncthreads();

    int lane = tid & 63, wid = tid >> 6;    // wid 0..15
    int fr = lane & 15, fq = lane >> 4;
    int s = wid * gridDim.x + blockIdx.x;   // bijective deal over 0..4095
    if (s >= nstrips) return;               // safe: no barriers after this point
    int row0 = s * 16;
    int arow = row0 + fr; if (arow >= M) arow = M - 1;
    const float* ap = X + (size_t)arow * FIN + fq * 8;

    f32x4 acc[8] = {};

    float4 c0 = *(const float4*)(ap + 0);
    float4 c1 = *(const float4*)(ap + 4);
    float4 c2 = *(const float4*)(ap + 32);
    float4 c3 = *(const float4*)(ap + 36);

    #pragma unroll
    for (int kk = 0; kk < 8; ++kk) {
        int k0 = kk * 64;
        float4 d0 = c0, d1 = c1, d2 = c2, d3 = c3;
        if (kk < 7) {
            c0 = *(const float4*)(ap + k0 + 64);
            c1 = *(const float4*)(ap + k0 + 68);
            c2 = *(const float4*)(ap + k0 + 96);
            c3 = *(const float4*)(ap + k0 + 100);
        }
        short8 af0, af1;
        af0[0] = (short)f2bf(d0.x); af0[1] = (short)f2bf(d0.y);
        af0[2] = (short)f2bf(d0.z); af0[3] = (short)f2bf(d0.w);
        af0[4] = (short)f2bf(d1.x); af0[5] = (short)f2bf(d1.y);
        af0[6] = (short)f2bf(d1.z); af0[7] = (short)f2bf(d1.w);
        af1[0] = (short)f2bf(d2.x); af1[1] = (short)f2bf(d2.y);
        af1[2] = (short)f2bf(d2.z); af1[3] = (short)f2bf(d2.w);
        af1[4] = (short)f2bf(d3.x); af1[5] = (short)f2bf(d3.y);
        af1[6] = (short)f2bf(d3.z); af1[7] = (short)f2bf(d3.w);

        int cb0 = k0 * 2 + fq * 16;
        #pragma unroll
        for (int c = 0; c < 8; ++c) {
            int br = c * 16 + fr;
            short8 b0 = *(const short8*)((const char*)Bs + br * 1024 +
                                         ((unsigned)cb0 ^ ((unsigned)(br & 7) << 4)));
            acc[c] = __builtin_amdgcn_mfma_f32_16x16x32_bf16(af0, b0, acc[c], 0, 0, 0);
        }
        int cb1 = cb0 + 64;
        #pragma unroll
        for (int c = 0; c < 8; ++c) {
            int br = c * 16 + fr;
            short8 b1 = *(const short8*)((const char*)Bs + br * 1024 +
                                         ((unsigned)cb1 ^ ((unsigned)(br & 7) << 4)));
            acc[c] = __builtin_amdgcn_mfma_f32_16x16x32_bf16(af1, b1, acc[c], 0, 0, 0);
        }
    }

    // store bf16: col = c*16+fr, row = row0 + fq*4 + j
    #pragma unroll
    for (int c = 0; c < 8; ++c) {
        #pragma unroll
        for (int j = 0; j < 4; ++j) {
            int row = row0 + fq * 4 + j;
            if (row < M) out[(size_t)row * FH + c * 16 + fr] = f2bf(acc[c][j]);
        }
    }
}

// ---------------- GEMM2: mu/logstd[M,64] = ah2b[M,128](bf16) @ W^T + b ------------

__global__ __launch_bounds__(512) void gemm2_kernel(
    const unsigned short* __restrict__ Xb,
    const unsigned short* __restrict__ Wh, const unsigned short* __restrict__ Wl,
    float* __restrict__ outA, float* __restrict__ outB,
    const float* __restrict__ biasA, const float* __restrict__ biasB,
    int M, int nstrips) {
    __shared__ __align__(16) unsigned short WhS[128 * 128];  // 32KB
    __shared__ __align__(16) unsigned short WlS[128 * 128];  // 32KB
    int tid = threadIdx.x;

    #pragma unroll
    for (int j = 0; j < 4; ++j) {
        int f = tid + j * 512;              // 16B chunk id, 0..2047
        int row = f >> 4;                   // 16 chunks per row
        unsigned addr = ((unsigned)f * 16u) ^ ((unsigned)(row & 7) << 4);
        *(short8*)((char*)WhS + addr) = ((const short8*)Wh)[f];
        *(short8*)((char*)WlS + addr) = ((const short8*)Wl)[f];
    }
    __syncthreads();

    int lane = tid & 63, wid = tid >> 6;
    int fr = lane & 15, fq = lane >> 4;
    int s = blockIdx.x * 8 + wid;
    if (s >= nstrips) return;
    int row0 = s * 16;
    int arow = row0 + fr; if (arow > M - 1) arow = M - 1;
    const unsigned short* ap = Xb + (size_t)arow * FH + fq * 8;

    short8 a0 = *(const short8*)(ap + 0);
    short8 a1 = *(const short8*)(ap + 32);
    short8 a2 = *(const short8*)(ap + 64);
    short8 a3 = *(const short8*)(ap + 96);

    f32x4 acc[8] = {};

    auto proc = [&](int k0, short8 a) {
        int cb = k0 * 2 + fq * 16;
        #pragma unroll
        for (int c = 0; c < 8; ++c) {
            int lr = c * 16 + fr;
            unsigned addr = ((unsigned)(lr * 256 + cb)) ^ ((unsigned)(lr & 7) << 4);
            short8 bh = *(const short8*)((const char*)WhS + addr);
            short8 bl = *(const short8*)((const char*)WlS + addr);
            acc[c] = __builtin_amdgcn_mfma_f32_16x16x32_bf16(a, bh, acc[c], 0, 0, 0);
            acc[c] = __builtin_amdgcn_mfma_f32_16x16x32_bf16(a, bl, acc[c], 0, 0, 0);
        }
    };
    proc(0, a0);
    proc(32, a1);
    proc(64, a2);
    proc(96, a3);

    #pragma unroll
    for (int c = 0; c < 8; ++c) {
        float* outp = (c < 4) ? outA : outB;
        const float* bp = (c < 4) ? biasA : biasB;
        int col = (c & 3) * 16 + fr;
        float bv = bp[col];
        #pragma unroll
        for (int j = 0; j < 4; ++j) {
            int row = row0 + fq * 4 + j;
            if (row < M) outp[(size_t)row * FO + col] = acc[c][j] + bv;
        }
    }
}

// ---------------- launch ----------------

extern "C" void kernel_launch(void* const* d_in, const int* in_sizes, int n_in,
                              void* d_out, int out_size, void* d_ws, size_t ws_size,
                              hipStream_t stream) {
    const float* x   = (const float*)d_in[0];
    const int*   ei  = (const int*)d_in[1];
    const float* W1  = (const float*)d_in[2];
    const float* b1  = (const float*)d_in[3];
    const float* Wmu = (const float*)d_in[4];
    const float* bmu = (const float*)d_in[5];
    const float* Wlg = (const float*)d_in[6];
    const float* blg = (const float*)d_in[7];

    int n = in_sizes[0] / FIN;   // 50000
    int E = in_sizes[1] / 2;     // 800000
    const int* src = ei;
    const int* dst = ei + E;
    const int nstrips = (n + 15) / 16; // 3125

    char* ws = (char*)d_ws;
    size_t off = 0;
    auto alloc = [&](size_t bytes) -> void* {
        void* p = ws + off;
        off = (off + bytes + 255) & ~((size_t)255);
        return p;
    };
    int*   cnt    = (int*)  alloc((size_t)(n + 4) * 4);
    int*   offs   = (int*)  alloc((size_t)(n + 1) * 4);
    int*   bsum   = (int*)  alloc(1024);
    float* dinv   = (float*)alloc((size_t)n * 4);
    int2*  esort  = (int2*) alloc((size_t)E * 8);
    unsigned short* hbf  = (unsigned short*)alloc((size_t)n * FH * 2);  // bf16 h
    unsigned short* h1bf = (unsigned short*)alloc((size_t)n * FH * 2);  // bf16 h1
    unsigned short* ah2b = (unsigned short*)alloc((size_t)n * FH * 2);  // bf16 ah2
    unsigned short* W1b = (unsigned short*)alloc((size_t)FH * FIN * 2);
    unsigned short* W2h = (unsigned short*)alloc((size_t)FH * FH * 2);
    unsigned short* W2l = (unsigned short*)alloc((size_t)FH * FH * 2);

    // one cooperative kernel: clear|convW -> count -> scan+dinv -> fill
    void* args[] = {(void*)&src, (void*)&dst, (void*)&E, (void*)&n,
                    (void*)&W1, (void*)&W1b, (void*)&Wmu, (void*)&Wlg,
                    (void*)&W2h, (void*)&W2l,
                    (void*)&cnt, (void*)&offs, (void*)&bsum, (void*)&dinv,
                    (void*)&esort};
    hipLaunchCooperativeKernel((void*)build_kernel, dim3(1024), dim3(256),
                               args, 0, stream);

    // layer 1: h = x @ W1^T   (whole W1 in 128KB LDS, full-machine grid, depth-1)
    gemm1_kernel<<<256, 1024, 128 * 1024, stream>>>(x, W1b, hbf, n, nstrips);
    // h1 = relu(A_norm @ h + b1)
    spmm_kernel<<<(n + 3) / 4, 256, 0, stream>>>(
        (const unsigned*)hbf, offs, esort, dinv, b1, (unsigned*)h1bf, n, 1);
    // ah2 = A_norm @ h1
    spmm_kernel<<<(n + 3) / 4, 256, 0, stream>>>(
        (const unsigned*)h1bf, offs, esort, dinv, nullptr, (unsigned*)ah2b, n, 0);
    // mu / logstd = ah2b @ W^T + b
    float* outmu = (float*)d_out;
    float* outlg = outmu + (size_t)n * FO;
    gemm2_kernel<<<(nstrips + 7) / 8, 512, 0, stream>>>(
        ah2b, W2h, W2l, outmu, outlg, bmu, blg, n, nstrips);
}

// Round 16
// 194.691 us; speedup vs baseline: 3.4251x; 3.4251x over previous
//
#include <hip/hip_runtime.h>

constexpr int FIN = 512;
constexpr int FH  = 128;
constexpr int FO  = 64;

typedef short short8 __attribute__((ext_vector_type(8)));
typedef float f32x4 __attribute__((ext_vector_type(4)));

__device__ __forceinline__ unsigned short f2bf(float f) {
    unsigned u = __float_as_uint(f);
    u += 0x7fffu + ((u >> 16) & 1u);   // RNE
    return (unsigned short)(u >> 16);
}
__device__ __forceinline__ float bf2f(unsigned short h) {
    return __uint_as_float((unsigned)h << 16);
}
__device__ __forceinline__ float bflo(unsigned v) { return __uint_as_float(v << 16); }
__device__ __forceinline__ float bfhi(unsigned v) { return __uint_as_float(v & 0xffff0000u); }

// ---------------- clear cnt ----------------

__global__ void clear_kernel(int4* __restrict__ p, int n4) {
    int i = blockIdx.x * blockDim.x + threadIdx.x;
    if (i < n4) p[i] = make_int4(0, 0, 0, 0);
}

// ---------------- fused pre-pass: count | convw1 | convw2 (block ranges) -----------

__global__ void pre_kernel(const int* __restrict__ dst, int* __restrict__ cnt, int E,
                           const float* __restrict__ W1, unsigned short* __restrict__ W1b,
                           const float* __restrict__ Wmu, const float* __restrict__ Wlg,
                           unsigned short* __restrict__ Wh, unsigned short* __restrict__ Wl,
                           int cntB) {
    int b = blockIdx.x;
    if (b < cntB) {
        int i = b * 256 + threadIdx.x;
        if (i < E) atomicAdd(&cnt[dst[i]], 1);
    } else if (b < cntB + 64) {
        int i = (b - cntB) * 256 + threadIdx.x;   // 0..16383 float4s
        float4 v = ((const float4*)W1)[i];
        ushort4 p;
        p.x = f2bf(v.x); p.y = f2bf(v.y); p.z = f2bf(v.z); p.w = f2bf(v.w);
        ((ushort4*)W1b)[i] = p;
    } else {
        int i = (b - cntB - 64) * 256 + threadIdx.x;  // 0..16383 elems
        int r = i >> 7, c = i & 127;
        float f = (r < 64) ? Wmu[r * 128 + c] : Wlg[(r - 64) * 128 + c];
        unsigned short h = f2bf(f);
        Wh[i] = h;
        Wl[i] = f2bf(f - bf2f(h));
    }
}

// ---------------- exclusive scan (3 kernels, 1024 elems/block) + fused dinv --------

__global__ void scan1_kernel(const int* __restrict__ cnt, int* __restrict__ offs,
                             int* __restrict__ bsum, float* __restrict__ dinv, int n) {
    __shared__ int sdata[256];
    int t = threadIdx.x;
    int base = blockIdx.x * 1024 + t * 4;
    int4 c = make_int4(0, 0, 0, 0);
    if (base + 3 < n) {
        c = *(const int4*)(cnt + base);
    } else {
        if (base + 0 < n) c.x = cnt[base + 0];
        if (base + 1 < n) c.y = cnt[base + 1];
        if (base + 2 < n) c.z = cnt[base + 2];
        if (base + 3 < n) c.w = cnt[base + 3];
    }
    // fused dinv = rsqrt(deg+1)
    if (base + 0 < n) dinv[base + 0] = rsqrtf((float)(c.x + 1));
    if (base + 1 < n) dinv[base + 1] = rsqrtf((float)(c.y + 1));
    if (base + 2 < n) dinv[base + 2] = rsqrtf((float)(c.z + 1));
    if (base + 3 < n) dinv[base + 3] = rsqrtf((float)(c.w + 1));

    int s0 = c.x + c.y + c.z + c.w;
    sdata[t] = s0;
    __syncthreads();
    for (int off = 1; off < 256; off <<= 1) {
        int v = (t >= off) ? sdata[t - off] : 0;
        __syncthreads();
        sdata[t] += v;
        __syncthreads();
    }
    int excl = sdata[t] - s0;
    if (t == 255) bsum[blockIdx.x] = sdata[255];
    if (base + 0 < n) offs[base + 0] = excl;
    if (base + 1 < n) offs[base + 1] = excl + c.x;
    if (base + 2 < n) offs[base + 2] = excl + c.x + c.y;
    if (base + 3 < n) offs[base + 3] = excl + c.x + c.y + c.z;
}

__global__ void scan2_kernel(int* __restrict__ bsum, int nb) {
    __shared__ int sdata[256];
    int t = threadIdx.x;
    int v = (t < nb) ? bsum[t] : 0;
    sdata[t] = v;
    __syncthreads();
    for (int off = 1; off < 256; off <<= 1) {
        int u = (t >= off) ? sdata[t - off] : 0;
        __syncthreads();
        sdata[t] += u;
        __syncthreads();
    }
    if (t < nb) bsum[t] = sdata[t] - v;  // exclusive
}

__global__ void scan3_kernel(int* __restrict__ offs, const int* __restrict__ bsum,
                             int n, int E) {
    int i = blockIdx.x * blockDim.x + threadIdx.x;
    if (i < n) offs[i] += bsum[i >> 10];
    if (i == 0) offs[n] = E;
}

// ---------------- CSR fill: slot via atomicSub on cnt (no cursor buffer) -----------

__global__ void fill_kernel(const int* __restrict__ src, const int* __restrict__ dst,
                            const float* __restrict__ dinv, const int* __restrict__ offs,
                            int* __restrict__ cnt, int2* __restrict__ esort, int E) {
    int i = blockIdx.x * blockDim.x + threadIdx.x;
    if (i < E) {
        int s = src[i];
        int d = dst[i];
        int old = atomicSub(&cnt[d], 1);
        int pos = offs[d] + old - 1;
        float w = dinv[s] * dinv[d];
        esort[pos] = make_int2(s, __float_as_int(w));
    }
}

// ---------------- SpMM gather (bf16 table), unroll-8 (round-12 proven) -------------

__global__ void spmm_kernel(const unsigned int* __restrict__ hin, const int* __restrict__ offs,
                            const int2* __restrict__ esort, const float* __restrict__ dinv,
                            const float* __restrict__ bias, unsigned int* __restrict__ hout,
                            int n, int relu) {
    int gid = blockIdx.x * blockDim.x + threadIdx.x;
    int node = gid >> 6;            // one 64-lane wave per node
    int lane = threadIdx.x & 63;    // lane handles channels 2*lane, 2*lane+1
    if (node >= n) return;
    float di = dinv[node];
    unsigned hv = hin[(size_t)node * 64 + lane];
    float ax = di * di * bflo(hv);
    float ay = di * di * bfhi(hv);
    int p = offs[node];
    int end = offs[node + 1];
    // align p to even so int4 (2-edge) loads are 16B-aligned
    if ((p & 1) && p < end) {
        int2 e = esort[p];
        unsigned v = hin[(size_t)e.x * 64 + lane];
        float w = __int_as_float(e.y);
        ax = fmaf(w, bflo(v), ax); ay = fmaf(w, bfhi(v), ay);
        ++p;
    }
    for (; p + 8 <= end; p += 8) {
        int4 q0 = *(const int4*)(esort + p + 0);
        int4 q1 = *(const int4*)(esort + p + 2);
        int4 q2 = *(const int4*)(esort + p + 4);
        int4 q3 = *(const int4*)(esort + p + 6);
        unsigned v0 = hin[(size_t)q0.x * 64 + lane];
        unsigned v1 = hin[(size_t)q0.z * 64 + lane];
        unsigned v2 = hin[(size_t)q1.x * 64 + lane];
        unsigned v3 = hin[(size_t)q1.z * 64 + lane];
        unsigned v4 = hin[(size_t)q2.x * 64 + lane];
        unsigned v5 = hin[(size_t)q2.z * 64 + lane];
        unsigned v6 = hin[(size_t)q3.x * 64 + lane];
        unsigned v7 = hin[(size_t)q3.z * 64 + lane];
        float w0 = __int_as_float(q0.y), w1 = __int_as_float(q0.w);
        float w2 = __int_as_float(q1.y), w3 = __int_as_float(q1.w);
        float w4 = __int_as_float(q2.y), w5 = __int_as_float(q2.w);
        float w6 = __int_as_float(q3.y), w7 = __int_as_float(q3.w);
        ax = fmaf(w0, bflo(v0), ax); ay = fmaf(w0, bfhi(v0), ay);
        ax = fmaf(w1, bflo(v1), ax); ay = fmaf(w1, bfhi(v1), ay);
        ax = fmaf(w2, bflo(v2), ax); ay = fmaf(w2, bfhi(v2), ay);
        ax = fmaf(w3, bflo(v3), ax); ay = fmaf(w3, bfhi(v3), ay);
        ax = fmaf(w4, bflo(v4), ax); ay = fmaf(w4, bfhi(v4), ay);
        ax = fmaf(w5, bflo(v5), ax); ay = fmaf(w5, bfhi(v5), ay);
        ax = fmaf(w6, bflo(v6), ax); ay = fmaf(w6, bfhi(v6), ay);
        ax = fmaf(w7, bflo(v7), ax); ay = fmaf(w7, bfhi(v7), ay);
    }
    for (; p + 2 <= end; p += 2) {
        int4 q = *(const int4*)(esort + p);
        unsigned v0 = hin[(size_t)q.x * 64 + lane];
        unsigned v1 = hin[(size_t)q.z * 64 + lane];
        float w0 = __int_as_float(q.y), w1 = __int_as_float(q.w);
        ax = fmaf(w0, bflo(v0), ax); ay = fmaf(w0, bfhi(v0), ay);
        ax = fmaf(w1, bflo(v1), ax); ay = fmaf(w1, bfhi(v1), ay);
    }
    if (p < end) {
        int2 e = esort[p];
        unsigned v = hin[(size_t)e.x * 64 + lane];
        float w = __int_as_float(e.y);
        ax = fmaf(w, bflo(v), ax); ay = fmaf(w, bfhi(v), ay);
    }
    if (bias) {
        float2 b = ((const float2*)bias)[lane];
        ax += b.x; ay += b.y;
    }
    if (relu) { ax = fmaxf(ax, 0.f); ay = fmaxf(ay, 0.f); }
    unsigned o = (unsigned)f2bf(ax) | ((unsigned)f2bf(ay) << 16);
    hout[(size_t)node * 64 + lane] = o;
}

// ---------------- GEMM1: h[M,128](bf16) = X[M,512] @ W1b[128,512]^T ----------------
// Persistent whole-W1 in LDS (128KB, swizzled). Grid = 256 (one block/CU); strips
// dealt bijectively s = wid*grid + blk. Depth-1 prefetch (fits 64 VGPR, no scratch).

__global__ __launch_bounds__(1024, 4) void gemm1_kernel(
    const float* __restrict__ X, const unsigned short* __restrict__ Wb,
    unsigned short* __restrict__ out, int M, int nstrips) {
    extern __shared__ __align__(16) unsigned short Bs[];   // 128 KB
    int tid = threadIdx.x;

    #pragma unroll
    for (int j = 0; j < 8; ++j) {
        int f = tid + j * 1024;             // chunk id
        int row = f >> 6;                   // 64 chunks (1024B) per row
        unsigned addr = ((unsigned)f << 4) ^ ((unsigned)(row & 7) << 4);
        *(short8*)((char*)Bs + addr) = ((const short8*)Wb)[f];
    }
    __syncthreads();

    int lane = tid & 63, wid = tid >> 6;    // wid 0..15
    int fr = lane & 15, fq = lane >> 4;
    int s = wid * gridDim.x + blockIdx.x;   // bijective deal over 0..4095
    if (s >= nstrips) return;               // safe: no barriers after this point
    int row0 = s * 16;
    int arow = row0 + fr; if (arow >= M) arow = M - 1;
    const float* ap = X + (size_t)arow * FIN + fq * 8;

    f32x4 acc[8] = {};

    float4 c0 = *(const float4*)(ap + 0);
    float4 c1 = *(const float4*)(ap + 4);
    float4 c2 = *(const float4*)(ap + 32);
    float4 c3 = *(const float4*)(ap + 36);

    #pragma unroll
    for (int kk = 0; kk < 8; ++kk) {
        int k0 = kk * 64;
        float4 d0 = c0, d1 = c1, d2 = c2, d3 = c3;
        if (kk < 7) {
            c0 = *(const float4*)(ap + k0 + 64);
            c1 = *(const float4*)(ap + k0 + 68);
            c2 = *(const float4*)(ap + k0 + 96);
            c3 = *(const float4*)(ap + k0 + 100);
        }
        short8 af0, af1;
        af0[0] = (short)f2bf(d0.x); af0[1] = (short)f2bf(d0.y);
        af0[2] = (short)f2bf(d0.z); af0[3] = (short)f2bf(d0.w);
        af0[4] = (short)f2bf(d1.x); af0[5] = (short)f2bf(d1.y);
        af0[6] = (short)f2bf(d1.z); af0[7] = (short)f2bf(d1.w);
        af1[0] = (short)f2bf(d2.x); af1[1] = (short)f2bf(d2.y);
        af1[2] = (short)f2bf(d2.z); af1[3] = (short)f2bf(d2.w);
        af1[4] = (short)f2bf(d3.x); af1[5] = (short)f2bf(d3.y);
        af1[6] = (short)f2bf(d3.z); af1[7] = (short)f2bf(d3.w);

        int cb0 = k0 * 2 + fq * 16;
        #pragma unroll
        for (int c = 0; c < 8; ++c) {
            int br = c * 16 + fr;
            short8 b0 = *(const short8*)((const char*)Bs + br * 1024 +
                                         ((unsigned)cb0 ^ ((unsigned)(br & 7) << 4)));
            acc[c] = __builtin_amdgcn_mfma_f32_16x16x32_bf16(af0, b0, acc[c], 0, 0, 0);
        }
        int cb1 = cb0 + 64;
        #pragma unroll
        for (int c = 0; c < 8; ++c) {
            int br = c * 16 + fr;
            short8 b1 = *(const short8*)((const char*)Bs + br * 1024 +
                                         ((unsigned)cb1 ^ ((unsigned)(br & 7) << 4)));
            acc[c] = __builtin_amdgcn_mfma_f32_16x16x32_bf16(af1, b1, acc[c], 0, 0, 0);
        }
    }

    // store bf16: col = c*16+fr, row = row0 + fq*4 + j
    #pragma unroll
    for (int c = 0; c < 8; ++c) {
        #pragma unroll
        for (int j = 0; j < 4; ++j) {
            int row = row0 + fq * 4 + j;
            if (row < M) out[(size_t)row * FH + c * 16 + fr] = f2bf(acc[c][j]);
        }
    }
}

// ---------------- GEMM2: mu/logstd[M,64] = ah2b[M,128](bf16) @ W^T + b ------------

__global__ __launch_bounds__(512) void gemm2_kernel(
    const unsigned short* __restrict__ Xb,
    const unsigned short* __restrict__ Wh, const unsigned short* __restrict__ Wl,
    float* __restrict__ outA, float* __restrict__ outB,
    const float* __restrict__ biasA, const float* __restrict__ biasB,
    int M, int nstrips) {
    __shared__ __align__(16) unsigned short WhS[128 * 128];  // 32KB
    __shared__ __align__(16) unsigned short WlS[128 * 128];  // 32KB
    int tid = threadIdx.x;

    #pragma unroll
    for (int j = 0; j < 4; ++j) {
        int f = tid + j * 512;              // 16B chunk id, 0..2047
        int row = f >> 4;                   // 16 chunks per row
        unsigned addr = ((unsigned)f * 16u) ^ ((unsigned)(row & 7) << 4);
        *(short8*)((char*)WhS + addr) = ((const short8*)Wh)[f];
        *(short8*)((char*)WlS + addr) = ((const short8*)Wl)[f];
    }
    __syncthreads();

    int lane = tid & 63, wid = tid >> 6;
    int fr = lane & 15, fq = lane >> 4;
    int s = blockIdx.x * 8 + wid;
    if (s >= nstrips) return;
    int row0 = s * 16;
    int arow = row0 + fr; if (arow > M - 1) arow = M - 1;
    const unsigned short* ap = Xb + (size_t)arow * FH + fq * 8;

    short8 a0 = *(const short8*)(ap + 0);
    short8 a1 = *(const short8*)(ap + 32);
    short8 a2 = *(const short8*)(ap + 64);
    short8 a3 = *(const short8*)(ap + 96);

    f32x4 acc[8] = {};

    auto proc = [&](int k0, short8 a) {
        int cb = k0 * 2 + fq * 16;
        #pragma unroll
        for (int c = 0; c < 8; ++c) {
            int lr = c * 16 + fr;
            unsigned addr = ((unsigned)(lr * 256 + cb)) ^ ((unsigned)(lr & 7) << 4);
            short8 bh = *(const short8*)((const char*)WhS + addr);
            short8 bl = *(const short8*)((const char*)WlS + addr);
            acc[c] = __builtin_amdgcn_mfma_f32_16x16x32_bf16(a, bh, acc[c], 0, 0, 0);
            acc[c] = __builtin_amdgcn_mfma_f32_16x16x32_bf16(a, bl, acc[c], 0, 0, 0);
        }
    };
    proc(0, a0);
    proc(32, a1);
    proc(64, a2);
    proc(96, a3);

    #pragma unroll
    for (int c = 0; c < 8; ++c) {
        float* outp = (c < 4) ? outA : outB;
        const float* bp = (c < 4) ? biasA : biasB;
        int col = (c & 3) * 16 + fr;
        float bv = bp[col];
        #pragma unroll
        for (int j = 0; j < 4; ++j) {
            int row = row0 + fq * 4 + j;
            if (row < M) outp[(size_t)row * FO + col] = acc[c][j] + bv;
        }
    }
}

// ---------------- launch ----------------

extern "C" void kernel_launch(void* const* d_in, const int* in_sizes, int n_in,
                              void* d_out, int out_size, void* d_ws, size_t ws_size,
                              hipStream_t stream) {
    const float* x   = (const float*)d_in[0];
    const int*   ei  = (const int*)d_in[1];
    const float* W1  = (const float*)d_in[2];
    const float* b1  = (const float*)d_in[3];
    const float* Wmu = (const float*)d_in[4];
    const float* bmu = (const float*)d_in[5];
    const float* Wlg = (const float*)d_in[6];
    const float* blg = (const float*)d_in[7];

    const int n = in_sizes[0] / FIN;   // 50000
    const int E = in_sizes[1] / 2;     // 800000
    const int* src = ei;
    const int* dst = ei + E;
    const int nstrips = (n + 15) / 16; // 3125

    char* ws = (char*)d_ws;
    size_t off = 0;
    auto alloc = [&](size_t bytes) -> void* {
        void* p = ws + off;
        off = (off + bytes + 255) & ~((size_t)255);
        return p;
    };
    int*   cnt    = (int*)  alloc((size_t)(n + 4) * 4);
    int*   offs   = (int*)  alloc((size_t)(n + 1) * 4);
    int*   bsum   = (int*)  alloc(1024);
    float* dinv   = (float*)alloc((size_t)n * 4);
    int2*  esort  = (int2*) alloc((size_t)E * 8);
    unsigned short* hbf  = (unsigned short*)alloc((size_t)n * FH * 2);  // bf16 h
    unsigned short* h1bf = (unsigned short*)alloc((size_t)n * FH * 2);  // bf16 h1
    unsigned short* ah2b = (unsigned short*)alloc((size_t)n * FH * 2);  // bf16 ah2
    unsigned short* W1b = (unsigned short*)alloc((size_t)FH * FIN * 2);
    unsigned short* W2h = (unsigned short*)alloc((size_t)FH * FH * 2);
    unsigned short* W2l = (unsigned short*)alloc((size_t)FH * FH * 2);

    // clear cnt with our own kernel
    int n4 = (n + 3) / 4;  // 12500 int4s
    clear_kernel<<<(n4 + 255) / 256, 256, 0, stream>>>((int4*)cnt, n4);

    // fused: count + convw1 + convw2
    int cntB = (E + 255) / 256;  // 3125
    pre_kernel<<<cntB + 128, 256, 0, stream>>>(dst, cnt, E, W1, W1b, Wmu, Wlg, W2h, W2l, cntB);

    int nb = (n + 1023) / 1024;  // 49
    scan1_kernel<<<nb, 256, 0, stream>>>(cnt, offs, bsum, dinv, n);
    scan2_kernel<<<1, 256, 0, stream>>>(bsum, nb);
    scan3_kernel<<<(n + 255) / 256, 256, 0, stream>>>(offs, bsum, n, E);

    // fill: slot via atomicSub(cnt)
    fill_kernel<<<(E + 255) / 256, 256, 0, stream>>>(src, dst, dinv, offs, cnt, esort, E);

    // layer 1: h = x @ W1^T   (whole W1 in 128KB LDS, full-machine grid, depth-1)
    gemm1_kernel<<<256, 1024, 128 * 1024, stream>>>(x, W1b, hbf, n, nstrips);
    // h1 = relu(A_norm @ h + b1)
    spmm_kernel<<<(n + 3) / 4, 256, 0, stream>>>(
        (const unsigned*)hbf, offs, esort, dinv, b1, (unsigned*)h1bf, n, 1);
    // ah2 = A_norm @ h1
    spmm_kernel<<<(n + 3) / 4, 256, 0, stream>>>(
        (const unsigned*)h1bf, offs, esort, dinv, nullptr, (unsigned*)ah2b, n, 0);
    // mu / logstd = ah2b @ W^T + b
    float* outmu = (float*)d_out;
    float* outlg = outmu + (size_t)n * FO;
    gemm2_kernel<<<(nstrips + 7) / 8, 512, 0, stream>>>(
        ah2b, W2h, W2l, outmu, outlg, bmu, blg, n, nstrips);
}